// Round 1
// 319.754 us; speedup vs baseline: 1.0488x; 1.0488x over previous
//
#include <hip/hip_runtime.h>

// EfConv forward, CSR-based (no fp32 atomics):
//   1. t = node_feat @ W^T  (+ fused: zero deg)        [N,64]
//   2. deg[d] = #edges with dst==d   (int atomics, int4-vectorized)
//   3. offsets = exclusive_scan(deg) (3-kernel scan)
//   4. permute: pos=cursor[dst[e]]++; pairs[pos]={src[e], e}  (one 8B scatter)
//   5. aggregate: per node n (one wave, lanes=o), 4-edge unrolled gather chains:
//        out[n,k,o] = b[o] + sum_{j in row n} ef[pairs[j].y,k] * t[pairs[j].x,o]
//      out written with NONTEMPORAL stores (write-once stream; keep L2/L3 for gathers).

#define FEATS 64
#define EDGE_DIM 8

// ---- Kernel 1: t[n][o] = sum_i nf[n][i] * W[o][i]; also zeroes deg ----
__global__ void __launch_bounds__(256) transform_kernel(
    const float* __restrict__ nf, const float* __restrict__ W,
    float* __restrict__ t, int* __restrict__ deg, int n_nodes)
{
    __shared__ float sWt[FEATS * 65];
    __shared__ float srow[4][FEATS];
    const int tid = threadIdx.x;

    // fused deg zeroing (first 196 blocks cover all nodes)
    int gid = blockIdx.x * 256 + tid;
    if (gid < n_nodes) deg[gid] = 0;

    #pragma unroll
    for (int base = 0; base < FEATS * FEATS; base += 256) {
        int idx = base + tid;
        int o = idx >> 6;
        int i = idx & 63;
        sWt[i * 65 + o] = W[idx];
    }

    const int r = tid >> 6;
    const int o = tid & 63;
    const int node = blockIdx.x * 4 + r;
    if (node < n_nodes) srow[r][o] = nf[(long)node * FEATS + o];
    __syncthreads();

    if (node >= n_nodes) return;
    float sum = 0.f;
    #pragma unroll
    for (int i = 0; i < FEATS; i++)
        sum += srow[r][i] * sWt[i * 65 + o];
    t[(long)node * FEATS + o] = sum;
}

// ---- Kernel 2: histogram of dst (4 edges/thread) ----
__global__ void __launch_bounds__(256) hist_kernel(
    const int* __restrict__ dst, int* __restrict__ deg, int n_edges)
{
    int i4 = (blockIdx.x * 256 + threadIdx.x) * 4;
    if (i4 + 3 < n_edges) {
        int4 d = *(const int4*)(dst + i4);
        atomicAdd(&deg[d.x], 1);
        atomicAdd(&deg[d.y], 1);
        atomicAdd(&deg[d.z], 1);
        atomicAdd(&deg[d.w], 1);
    } else {
        for (int e = i4; e < n_edges; ++e) atomicAdd(&deg[dst[e]], 1);
    }
}

// ---- Kernel 3a: per-block partial sums of deg ----
__global__ void __launch_bounds__(256) partials_kernel(
    const int* __restrict__ deg, int* __restrict__ partials, int n)
{
    __shared__ int s[256];
    int i = blockIdx.x * 256 + threadIdx.x;
    s[threadIdx.x] = (i < n) ? deg[i] : 0;
    __syncthreads();
    for (int off = 128; off > 0; off >>= 1) {
        if (threadIdx.x < off) s[threadIdx.x] += s[threadIdx.x + off];
        __syncthreads();
    }
    if (threadIdx.x == 0) partials[blockIdx.x] = s[0];
}

// ---- Kernel 3b: exclusive scan of partials (single block, nb <= 256) ----
__global__ void __launch_bounds__(256) scan_partials_kernel(
    const int* __restrict__ partials, int* __restrict__ pscan, int nb)
{
    __shared__ int s[256];
    int tid = threadIdx.x;
    s[tid] = (tid < nb) ? partials[tid] : 0;
    for (int off = 1; off < 256; off <<= 1) {
        __syncthreads();
        int x = (tid >= off) ? s[tid - off] : 0;
        __syncthreads();
        s[tid] += x;
    }
    __syncthreads();
    pscan[tid] = (tid == 0) ? 0 : s[tid - 1];
}

// ---- Kernel 3c: block-local exclusive scan + add partial offset ----
__global__ void __launch_bounds__(256) scan_addback_kernel(
    const int* __restrict__ deg, const int* __restrict__ pscan,
    int* __restrict__ offsets, int* __restrict__ cursor,
    int n, int n_edges)
{
    __shared__ int s[256];
    int tid = threadIdx.x;
    int i = blockIdx.x * 256 + tid;
    int v = (i < n) ? deg[i] : 0;
    s[tid] = v;
    for (int off = 1; off < 256; off <<= 1) {
        __syncthreads();
        int x = (tid >= off) ? s[tid - off] : 0;
        __syncthreads();
        s[tid] += x;
    }
    __syncthreads();
    if (i < n) {
        int excl = pscan[blockIdx.x] + s[tid] - v;   // inclusive - self = exclusive
        offsets[i] = excl;
        cursor[i]  = excl;
    }
    if (blockIdx.x == 0 && tid == 0) offsets[n] = n_edges;
}

// ---- Kernel 4: permute edges into dst-sorted order, fused (src,e) records ----
__global__ void __launch_bounds__(256) permute_kernel(
    const int* __restrict__ src, const int* __restrict__ dst,
    int* __restrict__ cursor, int2* __restrict__ pairs, int n_edges)
{
    int i4 = (blockIdx.x * 256 + threadIdx.x) * 4;
    if (i4 + 3 < n_edges) {
        int4 s = *(const int4*)(src + i4);
        int4 d = *(const int4*)(dst + i4);
        int p;
        p = atomicAdd(&cursor[d.x], 1); pairs[p] = make_int2(s.x, i4 + 0);
        p = atomicAdd(&cursor[d.y], 1); pairs[p] = make_int2(s.y, i4 + 1);
        p = atomicAdd(&cursor[d.z], 1); pairs[p] = make_int2(s.z, i4 + 2);
        p = atomicAdd(&cursor[d.w], 1); pairs[p] = make_int2(s.w, i4 + 3);
    } else {
        for (int e = i4; e < n_edges; ++e) {
            int p = atomicAdd(&cursor[dst[e]], 1);
            pairs[p] = make_int2(src[e], e);
        }
    }
}

// ---- Kernel 5: per-node aggregation (one wave per node, lanes = o) ----
#define FMA8(A0, A1, TV)                                \
    acc[0] += A0.x * TV; acc[1] += A0.y * TV;           \
    acc[2] += A0.z * TV; acc[3] += A0.w * TV;           \
    acc[4] += A1.x * TV; acc[5] += A1.y * TV;           \
    acc[6] += A1.z * TV; acc[7] += A1.w * TV;

__global__ void __launch_bounds__(256) aggregate_kernel(
    const float* __restrict__ t, const float* __restrict__ ef,
    const int2* __restrict__ pairs, const int* __restrict__ offsets,
    const float* __restrict__ b, float* __restrict__ out, int n_nodes)
{
    // node is wave-uniform; readfirstlane lets offsets/pairs/ef take the scalar path
    const int node = __builtin_amdgcn_readfirstlane(
        (int)((blockIdx.x * 256 + threadIdx.x) >> 6));
    const int o = threadIdx.x & 63;
    if (node >= n_nodes) return;

    const int beg = offsets[node];
    const int end = offsets[node + 1];
    float acc[EDGE_DIM];
    #pragma unroll
    for (int k = 0; k < EDGE_DIM; k++) acc[k] = 0.f;

    int j = beg;
    // 4-edge unroll: 4 independent gather chains in flight
    for (; j + 3 < end; j += 4) {
        int2 p0 = pairs[j];
        int2 p1 = pairs[j + 1];
        int2 p2 = pairs[j + 2];
        int2 p3 = pairs[j + 3];
        float tv0 = t[(long)p0.x * FEATS + o];
        float tv1 = t[(long)p1.x * FEATS + o];
        float tv2 = t[(long)p2.x * FEATS + o];
        float tv3 = t[(long)p3.x * FEATS + o];
        const float4* q0 = (const float4*)(ef + (long)p0.y * EDGE_DIM);
        const float4* q1 = (const float4*)(ef + (long)p1.y * EDGE_DIM);
        const float4* q2 = (const float4*)(ef + (long)p2.y * EDGE_DIM);
        const float4* q3 = (const float4*)(ef + (long)p3.y * EDGE_DIM);
        float4 a0 = q0[0], a1 = q0[1];
        float4 b0 = q1[0], b1 = q1[1];
        float4 c0 = q2[0], c1 = q2[1];
        float4 d0 = q3[0], d1 = q3[1];
        FMA8(a0, a1, tv0)
        FMA8(b0, b1, tv1)
        FMA8(c0, c1, tv2)
        FMA8(d0, d1, tv3)
    }
    for (; j < end; ++j) {
        int2 p = pairs[j];
        float tv = t[(long)p.x * FEATS + o];
        const float4* q = (const float4*)(ef + (long)p.y * EDGE_DIM);
        float4 a0 = q[0], a1 = q[1];
        FMA8(a0, a1, tv)
    }

    const float bo = b[o];
    float* op = out + (long)node * (EDGE_DIM * FEATS) + o;
    // out is write-once, never read: nontemporal -> don't evict gather working set
    #pragma unroll
    for (int k = 0; k < EDGE_DIM; k++)
        __builtin_nontemporal_store(acc[k] + bo, op + k * FEATS);
}

extern "C" void kernel_launch(void* const* d_in, const int* in_sizes, int n_in,
                              void* d_out, int out_size, void* d_ws, size_t ws_size,
                              hipStream_t stream) {
    const float* node_feat = (const float*)d_in[0];
    const float* edge_feat = (const float*)d_in[1];
    const float* W         = (const float*)d_in[2];
    const float* b         = (const float*)d_in[3];
    const int*   src       = (const int*)d_in[4];
    const int*   dst       = (const int*)d_in[5];
    float* out = (float*)d_out;

    const int n_nodes = in_sizes[0] / FEATS;
    const int n_edges = in_sizes[4];
    const int nb_nodes = (n_nodes + 255) / 256;        // blocks over nodes (<=256 required)
    const int nb_e4    = (n_edges + 1023) / 1024;      // 4 edges per thread

    // workspace layout (4B units)
    int* w = (int*)d_ws;
    float* t      = (float*)w;                         // N*64
    int* deg      = w + (long)n_nodes * FEATS;         // N
    int* offsets  = deg + n_nodes;                     // N+1
    int* cursor   = offsets + n_nodes + 1;             // N
    int* partials = cursor + n_nodes;                  // 256
    int* pscan    = partials + 256;                    // 256
    uintptr_t paddr = (uintptr_t)(pscan + 256);
    paddr = (paddr + 7) & ~(uintptr_t)7;               // 8B-align for int2
    int2* pairs   = (int2*)paddr;                      // E

    transform_kernel<<<(n_nodes + 3) / 4, 256, 0, stream>>>(node_feat, W, t, deg, n_nodes);
    hist_kernel<<<nb_e4, 256, 0, stream>>>(dst, deg, n_edges);
    partials_kernel<<<nb_nodes, 256, 0, stream>>>(deg, partials, n_nodes);
    scan_partials_kernel<<<1, 256, 0, stream>>>(partials, pscan, nb_nodes);
    scan_addback_kernel<<<nb_nodes, 256, 0, stream>>>(deg, pscan, offsets, cursor,
                                                      n_nodes, n_edges);
    permute_kernel<<<nb_e4, 256, 0, stream>>>(src, dst, cursor, pairs, n_edges);

    const long total_ag = (long)n_nodes * 64;
    aggregate_kernel<<<(int)((total_ag + 255) / 256), 256, 0, stream>>>(
        t, edge_feat, pairs, offsets, b, out, n_nodes);
}

// Round 2
// 285.510 us; speedup vs baseline: 1.1746x; 1.1199x over previous
//
#include <hip/hip_runtime.h>

// EfConv forward, CSR-based (no fp32 atomics):
//   1. t = node_feat @ W^T  (+ fused: zero deg)        [N,64]
//   2. deg[d] = #edges with dst==d   (int atomics, int4-vectorized)
//   3. offsets = exclusive_scan(deg) (3-kernel scan)
//   4. permute: pos=cursor[dst[e]]++; srcs[pos]=src[e]; efs[pos][:]=ef[e][:]
//      (ef VALUES are reordered here, so aggregate never gathers ef)
//   5. aggregate: per node n (one wave, lanes=o), 8-wide masked chunks:
//        out[n,k,o] = b[o] + sum_{j in row n} efs[j,k] * t[srcs[j],o]
//      srcs/efs reads are wave-uniform (scalar path); only t is a gather.
//      out written with NONTEMPORAL stores (write-once stream).
// Fallback path (pairs + ef gather) used if workspace too small for efs.

#define FEATS 64
#define EDGE_DIM 8

// ---- Kernel 1: t[n][o] = sum_i nf[n][i] * W[o][i]; also zeroes deg ----
__global__ void __launch_bounds__(256) transform_kernel(
    const float* __restrict__ nf, const float* __restrict__ W,
    float* __restrict__ t, int* __restrict__ deg, int n_nodes)
{
    __shared__ float sWt[FEATS * 65];
    __shared__ float srow[4][FEATS];
    const int tid = threadIdx.x;

    int gid = blockIdx.x * 256 + tid;
    if (gid < n_nodes) deg[gid] = 0;

    #pragma unroll
    for (int base = 0; base < FEATS * FEATS; base += 256) {
        int idx = base + tid;
        int o = idx >> 6;
        int i = idx & 63;
        sWt[i * 65 + o] = W[idx];
    }

    const int r = tid >> 6;
    const int o = tid & 63;
    const int node = blockIdx.x * 4 + r;
    if (node < n_nodes) srow[r][o] = nf[(long)node * FEATS + o];
    __syncthreads();

    if (node >= n_nodes) return;
    float sum = 0.f;
    #pragma unroll
    for (int i = 0; i < FEATS; i++)
        sum += srow[r][i] * sWt[i * 65 + o];
    t[(long)node * FEATS + o] = sum;
}

// ---- Kernel 2: histogram of dst (4 edges/thread) ----
__global__ void __launch_bounds__(256) hist_kernel(
    const int* __restrict__ dst, int* __restrict__ deg, int n_edges)
{
    int i4 = (blockIdx.x * 256 + threadIdx.x) * 4;
    if (i4 + 3 < n_edges) {
        int4 d = *(const int4*)(dst + i4);
        atomicAdd(&deg[d.x], 1);
        atomicAdd(&deg[d.y], 1);
        atomicAdd(&deg[d.z], 1);
        atomicAdd(&deg[d.w], 1);
    } else {
        for (int e = i4; e < n_edges; ++e) atomicAdd(&deg[dst[e]], 1);
    }
}

// ---- Kernel 3a: per-block partial sums of deg ----
__global__ void __launch_bounds__(256) partials_kernel(
    const int* __restrict__ deg, int* __restrict__ partials, int n)
{
    __shared__ int s[256];
    int i = blockIdx.x * 256 + threadIdx.x;
    s[threadIdx.x] = (i < n) ? deg[i] : 0;
    __syncthreads();
    for (int off = 128; off > 0; off >>= 1) {
        if (threadIdx.x < off) s[threadIdx.x] += s[threadIdx.x + off];
        __syncthreads();
    }
    if (threadIdx.x == 0) partials[blockIdx.x] = s[0];
}

// ---- Kernel 3b: exclusive scan of partials (single block, nb <= 256) ----
__global__ void __launch_bounds__(256) scan_partials_kernel(
    const int* __restrict__ partials, int* __restrict__ pscan, int nb)
{
    __shared__ int s[256];
    int tid = threadIdx.x;
    s[tid] = (tid < nb) ? partials[tid] : 0;
    for (int off = 1; off < 256; off <<= 1) {
        __syncthreads();
        int x = (tid >= off) ? s[tid - off] : 0;
        __syncthreads();
        s[tid] += x;
    }
    __syncthreads();
    pscan[tid] = (tid == 0) ? 0 : s[tid - 1];
}

// ---- Kernel 3c: block-local exclusive scan + add partial offset ----
__global__ void __launch_bounds__(256) scan_addback_kernel(
    const int* __restrict__ deg, const int* __restrict__ pscan,
    int* __restrict__ offsets, int* __restrict__ cursor,
    int n, int n_edges)
{
    __shared__ int s[256];
    int tid = threadIdx.x;
    int i = blockIdx.x * 256 + tid;
    int v = (i < n) ? deg[i] : 0;
    s[tid] = v;
    for (int off = 1; off < 256; off <<= 1) {
        __syncthreads();
        int x = (tid >= off) ? s[tid - off] : 0;
        __syncthreads();
        s[tid] += x;
    }
    __syncthreads();
    if (i < n) {
        int excl = pscan[blockIdx.x] + s[tid] - v;   // inclusive - self = exclusive
        offsets[i] = excl;
        cursor[i]  = excl;
    }
    if (blockIdx.x == 0 && tid == 0) offsets[n] = n_edges;
}

// ---- Kernel 4 (full path): permute edges AND ef rows into dst-sorted order ----
__global__ void __launch_bounds__(256) permute_ef_kernel(
    const int* __restrict__ src, const int* __restrict__ dst,
    const float* __restrict__ ef, int* __restrict__ cursor,
    int* __restrict__ srcs, float* __restrict__ efs, int n_edges)
{
    int i4 = (blockIdx.x * 256 + threadIdx.x) * 4;
    if (i4 + 3 < n_edges) {
        int4 s = *(const int4*)(src + i4);
        int4 d = *(const int4*)(dst + i4);
        const float4* q = (const float4*)(ef + (long)i4 * EDGE_DIM);
        // 4 independent atomics in flight first
        int p0 = atomicAdd(&cursor[d.x], 1);
        int p1 = atomicAdd(&cursor[d.y], 1);
        int p2 = atomicAdd(&cursor[d.z], 1);
        int p3 = atomicAdd(&cursor[d.w], 1);
        float4 e0a = q[0], e0b = q[1], e1a = q[2], e1b = q[3];
        float4 e2a = q[4], e2b = q[5], e3a = q[6], e3b = q[7];
        srcs[p0] = s.x; srcs[p1] = s.y; srcs[p2] = s.z; srcs[p3] = s.w;
        float4* w0 = (float4*)(efs + (long)p0 * EDGE_DIM); w0[0] = e0a; w0[1] = e0b;
        float4* w1 = (float4*)(efs + (long)p1 * EDGE_DIM); w1[0] = e1a; w1[1] = e1b;
        float4* w2 = (float4*)(efs + (long)p2 * EDGE_DIM); w2[0] = e2a; w2[1] = e2b;
        float4* w3 = (float4*)(efs + (long)p3 * EDGE_DIM); w3[0] = e3a; w3[1] = e3b;
    } else {
        for (int e = i4; e < n_edges; ++e) {
            int p = atomicAdd(&cursor[dst[e]], 1);
            srcs[p] = src[e];
            const float4* q = (const float4*)(ef + (long)e * EDGE_DIM);
            float4* wv = (float4*)(efs + (long)p * EDGE_DIM);
            wv[0] = q[0]; wv[1] = q[1];
        }
    }
}

// ---- Kernel 5 (full path): per-node aggregation, sequential scalar ef ----
__global__ void __launch_bounds__(256) aggregate_seq_kernel(
    const float* __restrict__ t, const float* __restrict__ efs,
    const int* __restrict__ srcs, const int* __restrict__ offsets,
    const float* __restrict__ b, float* __restrict__ out, int n_nodes)
{
    const int node = __builtin_amdgcn_readfirstlane(
        (int)((blockIdx.x * 256 + threadIdx.x) >> 6));
    const int o = threadIdx.x & 63;
    if (node >= n_nodes) return;

    const int beg = offsets[node];
    const int end = offsets[node + 1];
    float acc[EDGE_DIM];
    #pragma unroll
    for (int k = 0; k < EDGE_DIM; k++) acc[k] = 0.f;

    if (end > beg) {
        const int last = end - 1;      // >= beg >= 0, so clamped idx always valid
        for (int j = beg; j < end; j += 8) {
            int sidx[8];
            #pragma unroll
            for (int u = 0; u < 8; u++) {
                int jj = j + u;
                sidx[u] = srcs[jj <= last ? jj : last];   // uniform clamp
            }
            float tv[8];
            #pragma unroll
            for (int u = 0; u < 8; u++)                    // 8 gathers in flight
                tv[u] = t[(long)sidx[u] * FEATS + o];
            #pragma unroll
            for (int u = 0; u < 8; u++) {
                int jj = j + u;
                int ej = jj <= last ? jj : last;
                float tvm = (jj <= last) ? tv[u] : 0.f;    // mask tail lanes
                #pragma unroll
                for (int k = 0; k < EDGE_DIM; k++)
                    acc[k] += efs[(long)ej * EDGE_DIM + k] * tvm;  // ef on scalar path
            }
        }
    }

    const float bo = b[o];
    float* op = out + (long)node * (EDGE_DIM * FEATS) + o;
    #pragma unroll
    for (int k = 0; k < EDGE_DIM; k++)
        __builtin_nontemporal_store(acc[k] + bo, op + k * FEATS);
}

// ================= fallback path (R1, pairs + ef gather) =================
__global__ void __launch_bounds__(256) permute_pairs_kernel(
    const int* __restrict__ src, const int* __restrict__ dst,
    int* __restrict__ cursor, int2* __restrict__ pairs, int n_edges)
{
    int i4 = (blockIdx.x * 256 + threadIdx.x) * 4;
    if (i4 + 3 < n_edges) {
        int4 s = *(const int4*)(src + i4);
        int4 d = *(const int4*)(dst + i4);
        int p;
        p = atomicAdd(&cursor[d.x], 1); pairs[p] = make_int2(s.x, i4 + 0);
        p = atomicAdd(&cursor[d.y], 1); pairs[p] = make_int2(s.y, i4 + 1);
        p = atomicAdd(&cursor[d.z], 1); pairs[p] = make_int2(s.z, i4 + 2);
        p = atomicAdd(&cursor[d.w], 1); pairs[p] = make_int2(s.w, i4 + 3);
    } else {
        for (int e = i4; e < n_edges; ++e) {
            int p = atomicAdd(&cursor[dst[e]], 1);
            pairs[p] = make_int2(src[e], e);
        }
    }
}

#define FMA8(A0, A1, TV)                                \
    acc[0] += A0.x * TV; acc[1] += A0.y * TV;           \
    acc[2] += A0.z * TV; acc[3] += A0.w * TV;           \
    acc[4] += A1.x * TV; acc[5] += A1.y * TV;           \
    acc[6] += A1.z * TV; acc[7] += A1.w * TV;

__global__ void __launch_bounds__(256) aggregate_pairs_kernel(
    const float* __restrict__ t, const float* __restrict__ ef,
    const int2* __restrict__ pairs, const int* __restrict__ offsets,
    const float* __restrict__ b, float* __restrict__ out, int n_nodes)
{
    const int node = __builtin_amdgcn_readfirstlane(
        (int)((blockIdx.x * 256 + threadIdx.x) >> 6));
    const int o = threadIdx.x & 63;
    if (node >= n_nodes) return;

    const int beg = offsets[node];
    const int end = offsets[node + 1];
    float acc[EDGE_DIM];
    #pragma unroll
    for (int k = 0; k < EDGE_DIM; k++) acc[k] = 0.f;

    int j = beg;
    for (; j + 3 < end; j += 4) {
        int2 p0 = pairs[j];
        int2 p1 = pairs[j + 1];
        int2 p2 = pairs[j + 2];
        int2 p3 = pairs[j + 3];
        float tv0 = t[(long)p0.x * FEATS + o];
        float tv1 = t[(long)p1.x * FEATS + o];
        float tv2 = t[(long)p2.x * FEATS + o];
        float tv3 = t[(long)p3.x * FEATS + o];
        const float4* q0 = (const float4*)(ef + (long)p0.y * EDGE_DIM);
        const float4* q1 = (const float4*)(ef + (long)p1.y * EDGE_DIM);
        const float4* q2 = (const float4*)(ef + (long)p2.y * EDGE_DIM);
        const float4* q3 = (const float4*)(ef + (long)p3.y * EDGE_DIM);
        float4 a0 = q0[0], a1 = q0[1];
        float4 b0 = q1[0], b1 = q1[1];
        float4 c0 = q2[0], c1 = q2[1];
        float4 d0 = q3[0], d1 = q3[1];
        FMA8(a0, a1, tv0)
        FMA8(b0, b1, tv1)
        FMA8(c0, c1, tv2)
        FMA8(d0, d1, tv3)
    }
    for (; j < end; ++j) {
        int2 p = pairs[j];
        float tv = t[(long)p.x * FEATS + o];
        const float4* q = (const float4*)(ef + (long)p.y * EDGE_DIM);
        float4 a0 = q[0], a1 = q[1];
        FMA8(a0, a1, tv)
    }

    const float bo = b[o];
    float* op = out + (long)node * (EDGE_DIM * FEATS) + o;
    #pragma unroll
    for (int k = 0; k < EDGE_DIM; k++)
        __builtin_nontemporal_store(acc[k] + bo, op + k * FEATS);
}

extern "C" void kernel_launch(void* const* d_in, const int* in_sizes, int n_in,
                              void* d_out, int out_size, void* d_ws, size_t ws_size,
                              hipStream_t stream) {
    const float* node_feat = (const float*)d_in[0];
    const float* edge_feat = (const float*)d_in[1];
    const float* W         = (const float*)d_in[2];
    const float* b         = (const float*)d_in[3];
    const int*   src       = (const int*)d_in[4];
    const int*   dst       = (const int*)d_in[5];
    float* out = (float*)d_out;

    const int n_nodes = in_sizes[0] / FEATS;
    const int n_edges = in_sizes[4];
    const int nb_nodes = (n_nodes + 255) / 256;        // blocks over nodes (<=256 required)
    const int nb_e4    = (n_edges + 1023) / 1024;      // 4 edges per thread

    // common workspace prefix (4B units)
    int* w = (int*)d_ws;
    float* t      = (float*)w;                         // N*64
    int* deg      = w + (long)n_nodes * FEATS;         // N
    int* offsets  = deg + n_nodes;                     // N+1
    int* cursor   = offsets + n_nodes + 1;             // N
    int* partials = cursor + n_nodes;                  // 256
    int* pscan    = partials + 256;                    // 256
    int* tail     = pscan + 256;

    // full path needs: srcs (E ints) + efs (E*8 floats, 32B-aligned)
    uintptr_t sa = (uintptr_t)tail;
    int* srcs = (int*)sa;
    uintptr_t ea = (sa + (size_t)n_edges * 4 + 31) & ~(uintptr_t)31;
    float* efs = (float*)ea;
    size_t full_end = (ea - (uintptr_t)d_ws) + (size_t)n_edges * EDGE_DIM * 4;
    bool use_full = full_end <= ws_size;

    transform_kernel<<<(n_nodes + 3) / 4, 256, 0, stream>>>(node_feat, W, t, deg, n_nodes);
    hist_kernel<<<nb_e4, 256, 0, stream>>>(dst, deg, n_edges);
    partials_kernel<<<nb_nodes, 256, 0, stream>>>(deg, partials, n_nodes);
    scan_partials_kernel<<<1, 256, 0, stream>>>(partials, pscan, nb_nodes);
    scan_addback_kernel<<<nb_nodes, 256, 0, stream>>>(deg, pscan, offsets, cursor,
                                                      n_nodes, n_edges);

    const long total_ag = (long)n_nodes * 64;
    const int agg_blocks = (int)((total_ag + 255) / 256);

    if (use_full) {
        permute_ef_kernel<<<nb_e4, 256, 0, stream>>>(src, dst, edge_feat, cursor,
                                                     srcs, efs, n_edges);
        aggregate_seq_kernel<<<agg_blocks, 256, 0, stream>>>(
            t, efs, srcs, offsets, b, out, n_nodes);
    } else {
        uintptr_t paddr = (sa + 7) & ~(uintptr_t)7;
        int2* pairs = (int2*)paddr;                    // E int2
        permute_pairs_kernel<<<nb_e4, 256, 0, stream>>>(src, dst, cursor, pairs, n_edges);
        aggregate_pairs_kernel<<<agg_blocks, 256, 0, stream>>>(
            t, edge_feat, pairs, offsets, b, out, n_nodes);
    }
}